// Round 3
// baseline (279.086 us; speedup 1.0000x reference)
//
#include <hip/hip_runtime.h>

#define H 128
#define NPOS 10
#define ROWSB 64
#define BLOCK 512

using bf16x8 = __attribute__((ext_vector_type(8))) short;
using f32x4  = __attribute__((ext_vector_type(4))) float;

__device__ __forceinline__ unsigned short f2bf(float f) {
  unsigned u = __float_as_uint(f);
  u += 0x7FFFu + ((u >> 16) & 1u);   // round-to-nearest-even
  return (unsigned short)(u >> 16);
}

__device__ __forceinline__ float sigm(float x) {
  return __builtin_amdgcn_rcpf(1.0f + __builtin_amdgcn_exp2f(-1.44269504f * x));
}
__device__ __forceinline__ float tanh_f(float x) {
  return 2.0f * __builtin_amdgcn_rcpf(1.0f + __builtin_amdgcn_exp2f(-2.88539008f * x)) - 1.0f;
}

// wt[p][j][k] bf16: j<128 -> u col j = W_f[p*H+k][j]; j>=128 -> iou row (j-128), col p*H+k
// plus: histogram of pos into hist[]
__global__ void prep_wt(const float* __restrict__ Wf, const float* __restrict__ Wiou,
                        unsigned short* __restrict__ wt,
                        const int* __restrict__ posp, int* __restrict__ hist, int N) {
  int id = blockIdx.x * 256 + threadIdx.x;
  if (id < N) atomicAdd(&hist[posp[id]], 1);
  if (id >= NPOS * 512 * H) return;
  int k = id & 127;
  int j = (id >> 7) & 511;
  int p = id >> 16;
  float v = (j < H) ? Wf[(size_t)(p * H + k) * H + j]
                    : Wiou[(size_t)(j - H) * (NPOS * H) + p * H + k];
  wt[id] = f2bf(v);
}

// exclusive scan of hist -> cursor (scatter counters) + static block table
__global__ void scan_build(const int* __restrict__ hist, int* __restrict__ cursor,
                           int* __restrict__ blkpos, int* __restrict__ blkgs,
                           int* __restrict__ blkcnt, int maxb) {
  __shared__ int base[NPOS + 1], bb[NPOS + 1];
  int t = threadIdx.x;
  if (t == 0) {
    int run = 0, rb = 0;
    for (int p = 0; p < NPOS; ++p) {
      base[p] = run; bb[p] = rb;
      run += hist[p];
      rb += (hist[p] + ROWSB - 1) / ROWSB;
    }
    base[NPOS] = run; bb[NPOS] = rb;
  }
  __syncthreads();
  if (t < NPOS) cursor[t] = base[t];
  int nb = bb[NPOS];
  for (int b = t; b < maxb; b += 64) {
    if (b < nb) {
      int p = 0;
      while (bb[p + 1] <= b) ++p;
      int s = (b - bb[p]) * ROWSB;
      blkpos[b] = p;
      blkgs[b] = base[p] + s;
      blkcnt[b] = min(ROWSB, hist[p] - s);
    } else {
      blkpos[b] = -1;
    }
  }
}

__global__ void scatter_idx(const int* __restrict__ posp, int* __restrict__ cursor,
                            int* __restrict__ order, int N) {
  int i = blockIdx.x * 256 + threadIdx.x;
  if (i < N) {
    int s = atomicAdd(&cursor[posp[i]], 1);
    order[s] = i;
  }
}

__global__ __launch_bounds__(BLOCK, 4) void tree_lstm_main(
    const float* __restrict__ child_h, const float* __restrict__ child_c,
    const float* __restrict__ e1, const float* __restrict__ e2,
    const float* __restrict__ h_prev,
    const int* __restrict__ depthp, const int* __restrict__ maskp,
    const float* __restrict__ b_f, const float* __restrict__ b_iou,
    const unsigned short* __restrict__ wt,
    const int* __restrict__ order, const int* __restrict__ blkpos,
    const int* __restrict__ blkgs, const int* __restrict__ blkcnt,
    float* __restrict__ out, int N) {

  const int b = blockIdx.x;
  const int p = blkpos[b];
  if (p < 0) return;
  const int gs = blkgs[b], cnth = blkcnt[b];

  __shared__ unsigned short hs[ROWSB * H];   // 16 KB, XOR-swizzled bf16 h_cat
  __shared__ int rowg[ROWSB];

  const int t = threadIdx.x;
  const int wv = t >> 6, l = t & 63;
  const int l15 = l & 15, lhi = l >> 4;
  const int colr = wv * 16 + l15;            // wave's output column 0..127
  const int kof = lhi * 8;

  // ---- B panel into registers (one time, from L2-resident wt) ----
  const unsigned short* wb0 = wt + (size_t)p * 512 * H + (size_t)colr * H + kof;
  bf16x8 Bf[4][4];                           // [gate u,i,o,g][kk]
  #pragma unroll
  for (int g4 = 0; g4 < 4; ++g4)
    #pragma unroll
    for (int kk = 0; kk < 4; ++kk)
      Bf[g4][kk] = *(const bf16x8*)(wb0 + (size_t)g4 * 128 * H + kk * 32);

  if (t < ROWSB) rowg[t] = (t < cnth) ? order[gs + t] : -1;
  __syncthreads();

  // ---- stage A: 64 rows x 128 bf16 (child_h + depth-masked extras) ----
  #pragma unroll
  for (int i = 0; i < 2; ++i) {
    int id = i * BLOCK + t;                  // 0..1023
    int row = id >> 4, c8 = id & 15;
    int g = rowg[row];
    float4 a0 = {0.f, 0.f, 0.f, 0.f}, a1 = {0.f, 0.f, 0.f, 0.f};
    if (g >= 0) {
      const float4* ph = (const float4*)(child_h + (size_t)g * H + c8 * 8);
      a0 = ph[0]; a1 = ph[1];
      int dep = depthp[g];
      if (dep == 1 || dep == 2) {
        const float* ep = (dep == 1) ? e1 : e2;
        const float4* pe = (const float4*)(ep + (size_t)g * H + c8 * 8);
        float4 b0 = pe[0], b1 = pe[1];
        a0.x += b0.x; a0.y += b0.y; a0.z += b0.z; a0.w += b0.w;
        a1.x += b1.x; a1.y += b1.y; a1.z += b1.z; a1.w += b1.w;
      }
    }
    bf16x8 v;
    v[0] = (short)f2bf(a0.x); v[1] = (short)f2bf(a0.y);
    v[2] = (short)f2bf(a0.z); v[3] = (short)f2bf(a0.w);
    v[4] = (short)f2bf(a1.x); v[5] = (short)f2bf(a1.y);
    v[6] = (short)f2bf(a1.z); v[7] = (short)f2bf(a1.w);
    int wb = (row * 256 + c8 * 16) ^ ((row & 7) << 4);
    *(bf16x8*)((char*)hs + wb) = v;
  }
  __syncthreads();

  const size_t NH = (size_t)N * H;
  const float bfv = b_f[p * H + colr];
  const float b_i = b_iou[colr], b_o = b_iou[H + colr], b_g = b_iou[2 * H + colr];

  const int nchunk = (cnth + 15) >> 4;
  for (int c = 0; c < nchunk; ++c) {
    const int r0 = c * 16;

    // A fragments: row = r0 + (l&15), k = kk*32 + (l>>4)*8 + j
    const int arow = r0 + l15;
    bf16x8 afr[4];
    #pragma unroll
    for (int kk = 0; kk < 4; ++kk) {
      int rb = (arow * 256 + kk * 64 + lhi * 16) ^ ((arow & 7) << 4);
      afr[kk] = *(const bf16x8*)((const char*)hs + rb);
    }

    f32x4 au = {0.f, 0.f, 0.f, 0.f};
    f32x4 ai = {0.f, 0.f, 0.f, 0.f};
    f32x4 ao = {0.f, 0.f, 0.f, 0.f};
    f32x4 ag = {0.f, 0.f, 0.f, 0.f};
    #pragma unroll
    for (int kk = 0; kk < 4; ++kk) {
      au = __builtin_amdgcn_mfma_f32_16x16x32_bf16(afr[kk], Bf[0][kk], au, 0, 0, 0);
      ai = __builtin_amdgcn_mfma_f32_16x16x32_bf16(afr[kk], Bf[1][kk], ai, 0, 0, 0);
      ao = __builtin_amdgcn_mfma_f32_16x16x32_bf16(afr[kk], Bf[2][kk], ao, 0, 0, 0);
      ag = __builtin_amdgcn_mfma_f32_16x16x32_bf16(afr[kk], Bf[3][kk], ag, 0, 0, 0);
    }

    // epilogue: D row = (l>>4)*4 + q, col = l&15 (verified mapping)
    #pragma unroll
    for (int q = 0; q < 4; ++q) {
      int rr = r0 + lhi * 4 + q;
      if (rr < cnth) {
        int g = rowg[rr];
        size_t gi = (size_t)g * H + colr;
        float u = au[q] + bfv;
        float iv = ai[q] + b_i;
        float ov = ao[q] + b_o;
        float gv = ag[q] + b_g;
        float f = sigm(u);
        float credv = f * child_c[gi];
        float cnew = sigm(iv) * tanh_f(gv) + credv;
        float hnew = sigm(ov) * tanh_f(cnew);
        int mi = maskp[g];
        float m = (float)mi;
        float hp = (mi != 0) ? h_prev[gi] : 0.0f;
        float hv = hp * m + (1.0f - m) * hnew;
        float cv = credv * m + (1.0f - m) * cnew;
        out[gi] = hv;
        out[NH + gi] = cv;
      }
    }
  }
}

extern "C" void kernel_launch(void* const* d_in, const int* in_sizes, int n_in,
                              void* d_out, int out_size, void* d_ws, size_t ws_size,
                              hipStream_t stream) {
  const float* child_h = (const float*)d_in[0];
  const float* child_c = (const float*)d_in[1];
  const float* e1      = (const float*)d_in[2];
  const float* e2      = (const float*)d_in[3];
  const float* h_prev  = (const float*)d_in[4];
  const int*   posp    = (const int*)d_in[5];
  const int*   depthp  = (const int*)d_in[6];
  const int*   maskp   = (const int*)d_in[7];
  const float* W_f     = (const float*)d_in[8];
  const float* b_f     = (const float*)d_in[9];
  const float* W_iou   = (const float*)d_in[10];
  const float* b_iou   = (const float*)d_in[11];
  float* out = (float*)d_out;
  int N = in_sizes[0] / H;
  int maxb = NPOS + N / ROWSB;

  // ws layout
  unsigned short* wt = (unsigned short*)d_ws;          // 655360 * 2B
  int* hist   = (int*)((char*)d_ws + (size_t)NPOS * 512 * H * 2);
  int* cursor = hist + 16;
  int* blkpos = hist + 32;
  int* blkgs  = blkpos + maxb;
  int* blkcnt = blkgs + maxb;
  int* order  = blkcnt + maxb;

  hipMemsetAsync(hist, 0, 64, stream);
  hipLaunchKernelGGL(prep_wt, dim3((NPOS * 512 * H + 255) / 256), dim3(256), 0, stream,
                     W_f, W_iou, wt, posp, hist, N);
  hipLaunchKernelGGL(scan_build, dim3(1), dim3(64), 0, stream,
                     hist, cursor, blkpos, blkgs, blkcnt, maxb);
  hipLaunchKernelGGL(scatter_idx, dim3((N + 255) / 256), dim3(256), 0, stream,
                     posp, cursor, order, N);
  hipLaunchKernelGGL(tree_lstm_main, dim3(maxb), dim3(BLOCK), 0, stream,
                     child_h, child_c, e1, e2, h_prev, depthp, maskp,
                     b_f, b_iou, wt, order, blkpos, blkgs, blkcnt, out, N);
}

// Round 4
// 64.570 us; speedup vs baseline: 4.3222x; 4.3222x over previous
//
#include <hip/hip_runtime.h>

#define H 128
#define NPOS 10
#define ROWSB 64
#define BLOCK 512

using bf16x8 = __attribute__((ext_vector_type(8))) short;
using f32x4  = __attribute__((ext_vector_type(4))) float;

__device__ __forceinline__ unsigned short f2bf(float f) {
  unsigned u = __float_as_uint(f);
  u += 0x7FFFu + ((u >> 16) & 1u);   // round-to-nearest-even
  return (unsigned short)(u >> 16);
}

__device__ __forceinline__ float sigm(float x) {
  return __builtin_amdgcn_rcpf(1.0f + __builtin_amdgcn_exp2f(-1.44269504f * x));
}
__device__ __forceinline__ float tanh_f(float x) {
  return 2.0f * __builtin_amdgcn_rcpf(1.0f + __builtin_amdgcn_exp2f(-2.88539008f * x)) - 1.0f;
}

// wt[p][j][k] bf16: j<128 -> u col j = W_f[p*H+k][j]; j>=128 -> iou row (j-128), col p*H+k
// Fused: blocks [0,160): W_f transpose via LDS tiles; blocks [160,2080): W_iou direct copy.
__global__ void prep_wt(const float* __restrict__ Wf, const float* __restrict__ Wiou,
                        unsigned short* __restrict__ wt) {
  int b = blockIdx.x, t = threadIdx.x;
  if (b < NPOS * 16) {
    // transpose path: p = b/16, jt = (b%16)/4, kt = b%4; 32x32 tile
    __shared__ float tile[32][33];
    int p = b >> 4, jt = (b >> 2) & 3, kt = b & 3;
    int tx = t & 31, ty = t >> 5;            // 32 x 8
    #pragma unroll
    for (int it = 0; it < 4; ++it) {
      int krow = kt * 32 + ty + it * 8;
      int j = jt * 32 + tx;
      tile[ty + it * 8][tx] = Wf[(size_t)(p * H + krow) * H + j];  // coalesced in j
    }
    __syncthreads();
    #pragma unroll
    for (int it = 0; it < 4; ++it) {
      int j2 = jt * 32 + ty + it * 8;
      int k2 = kt * 32 + tx;
      wt[(size_t)p * 512 * H + (size_t)j2 * H + k2] = f2bf(tile[tx][ty + it * 8]);
    }
  } else {
    // iou path: 10*384*128 elements
    int id = (b - NPOS * 16) * 256 + t;
    int p = id / 49152;
    int r = id - p * 49152;                  // r = (j-128)*128 + k
    int k = r & 127;
    float v = Wiou[(size_t)(r >> 7) * (NPOS * H) + p * H + k];
    wt[(size_t)p * 65536 + 16384 + r] = f2bf(v);
  }
}

// per-block LDS histogram -> 10 global atomics per block
__global__ void hist_k(const int* __restrict__ posp, int* __restrict__ hist, int N) {
  __shared__ int c[NPOS];
  int t = threadIdx.x;
  if (t < NPOS) c[t] = 0;
  __syncthreads();
  int i = blockIdx.x * 256 + t;
  if (i < N) atomicAdd(&c[posp[i]], 1);
  __syncthreads();
  if (t < NPOS && c[t] > 0) atomicAdd(&hist[t], c[t]);
}

// exclusive scan of hist -> cursor (range-reservation counters) + static block table
__global__ void scan_build(const int* __restrict__ hist, int* __restrict__ cursor,
                           int* __restrict__ blkpos, int* __restrict__ blkgs,
                           int* __restrict__ blkcnt, int maxb) {
  __shared__ int base[NPOS + 1], bb[NPOS + 1];
  int t = threadIdx.x;
  if (t == 0) {
    int run = 0, rb = 0;
    for (int p = 0; p < NPOS; ++p) {
      base[p] = run; bb[p] = rb;
      run += hist[p];
      rb += (hist[p] + ROWSB - 1) / ROWSB;
    }
    base[NPOS] = run; bb[NPOS] = rb;
  }
  __syncthreads();
  if (t < NPOS) cursor[t] = base[t];
  int nb = bb[NPOS];
  for (int b = t; b < maxb; b += 64) {
    if (b < nb) {
      int p = 0;
      while (bb[p + 1] <= b) ++p;
      int s = (b - bb[p]) * ROWSB;
      blkpos[b] = p;
      blkgs[b] = base[p] + s;
      blkcnt[b] = min(ROWSB, hist[p] - s);
    } else {
      blkpos[b] = -1;
    }
  }
}

// LDS local rank + per-(block,pos) global range reservation
__global__ void scatter_idx(const int* __restrict__ posp, int* __restrict__ cursor,
                            int* __restrict__ order, int N) {
  __shared__ int c[NPOS], bb[NPOS];
  int t = threadIdx.x;
  if (t < NPOS) c[t] = 0;
  __syncthreads();
  int i = blockIdx.x * 256 + t;
  int p = -1, r = 0;
  if (i < N) {
    p = posp[i];
    r = atomicAdd(&c[p], 1);
  }
  __syncthreads();
  if (t < NPOS) bb[t] = (c[t] > 0) ? atomicAdd(&cursor[t], c[t]) : 0;
  __syncthreads();
  if (p >= 0) order[bb[p] + r] = i;
}

__global__ __launch_bounds__(BLOCK, 4) void tree_lstm_main(
    const float* __restrict__ child_h, const float* __restrict__ child_c,
    const float* __restrict__ e1, const float* __restrict__ e2,
    const float* __restrict__ h_prev,
    const int* __restrict__ depthp, const int* __restrict__ maskp,
    const float* __restrict__ b_f, const float* __restrict__ b_iou,
    const unsigned short* __restrict__ wt,
    const int* __restrict__ order, const int* __restrict__ blkpos,
    const int* __restrict__ blkgs, const int* __restrict__ blkcnt,
    float* __restrict__ out, int N) {

  const int b = blockIdx.x;
  const int p = blkpos[b];
  if (p < 0) return;
  const int gs = blkgs[b], cnth = blkcnt[b];

  __shared__ unsigned short hs[ROWSB * H];   // 16 KB, XOR-swizzled bf16 h_cat
  __shared__ int rowg[ROWSB];

  const int t = threadIdx.x;
  const int wv = t >> 6, l = t & 63;
  const int l15 = l & 15, lhi = l >> 4;
  const int colr = wv * 16 + l15;            // wave's output column 0..127
  const int kof = lhi * 8;

  // ---- B panel into registers (one time, from L2-resident wt) ----
  const unsigned short* wb0 = wt + (size_t)p * 512 * H + (size_t)colr * H + kof;
  bf16x8 Bf[4][4];                           // [gate u,i,o,g][kk]
  #pragma unroll
  for (int g4 = 0; g4 < 4; ++g4)
    #pragma unroll
    for (int kk = 0; kk < 4; ++kk)
      Bf[g4][kk] = *(const bf16x8*)(wb0 + (size_t)g4 * 128 * H + kk * 32);

  if (t < ROWSB) rowg[t] = (t < cnth) ? order[gs + t] : -1;
  __syncthreads();

  // ---- stage A: 64 rows x 128 bf16 (child_h + depth-masked extras) ----
  #pragma unroll
  for (int i = 0; i < 2; ++i) {
    int id = i * BLOCK + t;                  // 0..1023
    int row = id >> 4, c8 = id & 15;
    int g = rowg[row];
    float4 a0 = {0.f, 0.f, 0.f, 0.f}, a1 = {0.f, 0.f, 0.f, 0.f};
    if (g >= 0) {
      const float4* ph = (const float4*)(child_h + (size_t)g * H + c8 * 8);
      a0 = ph[0]; a1 = ph[1];
      int dep = depthp[g];
      if (dep == 1 || dep == 2) {
        const float* ep = (dep == 1) ? e1 : e2;
        const float4* pe = (const float4*)(ep + (size_t)g * H + c8 * 8);
        float4 b0 = pe[0], b1 = pe[1];
        a0.x += b0.x; a0.y += b0.y; a0.z += b0.z; a0.w += b0.w;
        a1.x += b1.x; a1.y += b1.y; a1.z += b1.z; a1.w += b1.w;
      }
    }
    bf16x8 v;
    v[0] = (short)f2bf(a0.x); v[1] = (short)f2bf(a0.y);
    v[2] = (short)f2bf(a0.z); v[3] = (short)f2bf(a0.w);
    v[4] = (short)f2bf(a1.x); v[5] = (short)f2bf(a1.y);
    v[6] = (short)f2bf(a1.z); v[7] = (short)f2bf(a1.w);
    int wb = (row * 256 + c8 * 16) ^ ((row & 7) << 4);
    *(bf16x8*)((char*)hs + wb) = v;
  }
  __syncthreads();

  const size_t NH = (size_t)N * H;
  const float bfv = b_f[p * H + colr];
  const float b_i = b_iou[colr], b_o = b_iou[H + colr], b_g = b_iou[2 * H + colr];

  const int nchunk = (cnth + 15) >> 4;
  for (int c = 0; c < nchunk; ++c) {
    const int r0 = c * 16;

    // A fragments: row = r0 + (l&15), k = kk*32 + (l>>4)*8 + j
    const int arow = r0 + l15;
    bf16x8 afr[4];
    #pragma unroll
    for (int kk = 0; kk < 4; ++kk) {
      int rb = (arow * 256 + kk * 64 + lhi * 16) ^ ((arow & 7) << 4);
      afr[kk] = *(const bf16x8*)((const char*)hs + rb);
    }

    f32x4 au = {0.f, 0.f, 0.f, 0.f};
    f32x4 ai = {0.f, 0.f, 0.f, 0.f};
    f32x4 ao = {0.f, 0.f, 0.f, 0.f};
    f32x4 ag = {0.f, 0.f, 0.f, 0.f};
    #pragma unroll
    for (int kk = 0; kk < 4; ++kk) {
      au = __builtin_amdgcn_mfma_f32_16x16x32_bf16(afr[kk], Bf[0][kk], au, 0, 0, 0);
      ai = __builtin_amdgcn_mfma_f32_16x16x32_bf16(afr[kk], Bf[1][kk], ai, 0, 0, 0);
      ao = __builtin_amdgcn_mfma_f32_16x16x32_bf16(afr[kk], Bf[2][kk], ao, 0, 0, 0);
      ag = __builtin_amdgcn_mfma_f32_16x16x32_bf16(afr[kk], Bf[3][kk], ag, 0, 0, 0);
    }

    // epilogue: D row = (l>>4)*4 + q, col = l&15 (verified mapping)
    #pragma unroll
    for (int q = 0; q < 4; ++q) {
      int rr = r0 + lhi * 4 + q;
      if (rr < cnth) {
        int g = rowg[rr];
        size_t gi = (size_t)g * H + colr;
        float u = au[q] + bfv;
        float iv = ai[q] + b_i;
        float ov = ao[q] + b_o;
        float gv = ag[q] + b_g;
        float f = sigm(u);
        float credv = f * child_c[gi];
        float cnew = sigm(iv) * tanh_f(gv) + credv;
        float hnew = sigm(ov) * tanh_f(cnew);
        int mi = maskp[g];
        float m = (float)mi;
        float hp = (mi != 0) ? h_prev[gi] : 0.0f;
        float hv = hp * m + (1.0f - m) * hnew;
        float cv = credv * m + (1.0f - m) * cnew;
        out[gi] = hv;
        out[NH + gi] = cv;
      }
    }
  }
}

extern "C" void kernel_launch(void* const* d_in, const int* in_sizes, int n_in,
                              void* d_out, int out_size, void* d_ws, size_t ws_size,
                              hipStream_t stream) {
  const float* child_h = (const float*)d_in[0];
  const float* child_c = (const float*)d_in[1];
  const float* e1      = (const float*)d_in[2];
  const float* e2      = (const float*)d_in[3];
  const float* h_prev  = (const float*)d_in[4];
  const int*   posp    = (const int*)d_in[5];
  const int*   depthp  = (const int*)d_in[6];
  const int*   maskp   = (const int*)d_in[7];
  const float* W_f     = (const float*)d_in[8];
  const float* b_f     = (const float*)d_in[9];
  const float* W_iou   = (const float*)d_in[10];
  const float* b_iou   = (const float*)d_in[11];
  float* out = (float*)d_out;
  int N = in_sizes[0] / H;
  int maxb = NPOS + N / ROWSB;

  // ws layout
  unsigned short* wt = (unsigned short*)d_ws;          // 655360 * 2B
  int* hist   = (int*)((char*)d_ws + (size_t)NPOS * 512 * H * 2);
  int* cursor = hist + 16;
  int* blkpos = hist + 32;
  int* blkgs  = blkpos + maxb;
  int* blkcnt = blkgs + maxb;
  int* order  = blkcnt + maxb;

  hipMemsetAsync(hist, 0, 64, stream);
  hipLaunchKernelGGL(prep_wt, dim3(NPOS * 16 + (NPOS * 384 * H) / 256), dim3(256), 0, stream,
                     W_f, W_iou, wt);
  hipLaunchKernelGGL(hist_k, dim3((N + 255) / 256), dim3(256), 0, stream, posp, hist, N);
  hipLaunchKernelGGL(scan_build, dim3(1), dim3(64), 0, stream,
                     hist, cursor, blkpos, blkgs, blkcnt, maxb);
  hipLaunchKernelGGL(scatter_idx, dim3((N + 255) / 256), dim3(256), 0, stream,
                     posp, cursor, order, N);
  hipLaunchKernelGGL(tree_lstm_main, dim3(maxb), dim3(BLOCK), 0, stream,
                     child_h, child_c, e1, e2, h_prev, depthp, maskp,
                     b_f, b_iou, wt, order, blkpos, blkgs, blkcnt, out, N);
}

// Round 5
// 56.093 us; speedup vs baseline: 4.9754x; 1.1511x over previous
//
#include <hip/hip_runtime.h>

#define H 128
#define NPOS 10
#define ROWSB 128
#define BLOCK 512

using bf16x8 = __attribute__((ext_vector_type(8))) short;
using f32x4  = __attribute__((ext_vector_type(4))) float;

__device__ __forceinline__ unsigned short f2bf(float f) {
  unsigned u = __float_as_uint(f);
  u += 0x7FFFu + ((u >> 16) & 1u);   // round-to-nearest-even
  return (unsigned short)(u >> 16);
}

__device__ __forceinline__ float sigm(float x) {
  return __builtin_amdgcn_rcpf(1.0f + __builtin_amdgcn_exp2f(-1.44269504f * x));
}
__device__ __forceinline__ float tanh_f(float x) {
  return 2.0f * __builtin_amdgcn_rcpf(1.0f + __builtin_amdgcn_exp2f(-2.88539008f * x)) - 1.0f;
}

// wt[p][j][k] bf16: j<128 -> u col j = W_f[p*H+k][j]; j>=128 -> iou row (j-128), col p*H+k
__global__ void prep_wt(const float* __restrict__ Wf, const float* __restrict__ Wiou,
                        unsigned short* __restrict__ wt) {
  int b = blockIdx.x, t = threadIdx.x;
  if (b < NPOS * 16) {
    __shared__ float tile[32][33];
    int p = b >> 4, jt = (b >> 2) & 3, kt = b & 3;
    int tx = t & 31, ty = t >> 5;            // 32 x 8
    #pragma unroll
    for (int it = 0; it < 4; ++it) {
      int krow = kt * 32 + ty + it * 8;
      int j = jt * 32 + tx;
      tile[ty + it * 8][tx] = Wf[(size_t)(p * H + krow) * H + j];
    }
    __syncthreads();
    #pragma unroll
    for (int it = 0; it < 4; ++it) {
      int j2 = jt * 32 + ty + it * 8;
      int k2 = kt * 32 + tx;
      wt[(size_t)p * 512 * H + (size_t)j2 * H + k2] = f2bf(tile[tx][ty + it * 8]);
    }
  } else {
    int id = (b - NPOS * 16) * 256 + t;
    int p = id / 49152;
    int r = id - p * 49152;
    int k = r & 127;
    float v = Wiou[(size_t)(r >> 7) * (NPOS * H) + p * H + k];
    wt[(size_t)p * 65536 + 16384 + r] = f2bf(v);
  }
}

__global__ void hist_k(const int* __restrict__ posp, int* __restrict__ hist, int N) {
  __shared__ int c[NPOS];
  int t = threadIdx.x;
  if (t < NPOS) c[t] = 0;
  __syncthreads();
  int i = blockIdx.x * 256 + t;
  if (i < N) atomicAdd(&c[posp[i]], 1);
  __syncthreads();
  if (t < NPOS && c[t] > 0) atomicAdd(&hist[t], c[t]);
}

__global__ void scan_build(const int* __restrict__ hist, int* __restrict__ cursor,
                           int* __restrict__ blkpos, int* __restrict__ blkgs,
                           int* __restrict__ blkcnt, int maxb) {
  __shared__ int base[NPOS + 1], bb[NPOS + 1];
  int t = threadIdx.x;
  if (t == 0) {
    int run = 0, rb = 0;
    for (int p = 0; p < NPOS; ++p) {
      base[p] = run; bb[p] = rb;
      run += hist[p];
      rb += (hist[p] + ROWSB - 1) / ROWSB;
    }
    base[NPOS] = run; bb[NPOS] = rb;
  }
  __syncthreads();
  if (t < NPOS) cursor[t] = base[t];
  int nb = bb[NPOS];
  for (int b = t; b < maxb; b += 64) {
    if (b < nb) {
      int p = 0;
      while (bb[p + 1] <= b) ++p;
      int s = (b - bb[p]) * ROWSB;
      blkpos[b] = p;
      blkgs[b] = base[p] + s;
      blkcnt[b] = min(ROWSB, hist[p] - s);
    } else {
      blkpos[b] = -1;
    }
  }
}

__global__ void scatter_idx(const int* __restrict__ posp, int* __restrict__ cursor,
                            int* __restrict__ order, int N) {
  __shared__ int c[NPOS], bb[NPOS];
  int t = threadIdx.x;
  if (t < NPOS) c[t] = 0;
  __syncthreads();
  int i = blockIdx.x * 256 + t;
  int p = -1, r = 0;
  if (i < N) {
    p = posp[i];
    r = atomicAdd(&c[p], 1);
  }
  __syncthreads();
  if (t < NPOS) bb[t] = (c[t] > 0) ? atomicAdd(&cursor[t], c[t]) : 0;
  __syncthreads();
  if (p >= 0) order[bb[p] + r] = i;
}

__global__ __launch_bounds__(BLOCK, 2) void tree_lstm_main(
    const float* __restrict__ child_h, const float* __restrict__ child_c,
    const float* __restrict__ e1, const float* __restrict__ e2,
    const float* __restrict__ h_prev,
    const int* __restrict__ depthp, const int* __restrict__ maskp,
    const float* __restrict__ b_f, const float* __restrict__ b_iou,
    const unsigned short* __restrict__ wt,
    const int* __restrict__ order, const int* __restrict__ blkpos,
    const int* __restrict__ blkgs, const int* __restrict__ blkcnt,
    float* __restrict__ out, int N) {

  const int b = blockIdx.x;
  const int p = blkpos[b];
  if (p < 0) return;
  const int gs = blkgs[b], cnth = blkcnt[b];

  __shared__ unsigned short hs[ROWSB * H];   // 32 KB, XOR-swizzled bf16 h_cat
  __shared__ int rowg[ROWSB];

  const int t = threadIdx.x;
  const int wv = t >> 6, l = t & 63;
  const int l15 = l & 15, lhi = l >> 4;
  const int colr = wv * 16 + l15;            // wave's output column 0..127
  const int kof = lhi * 8;

  // ---- B panel into registers, held for all 8 chunks (needs VGPR headroom) ----
  const unsigned short* wb0 = wt + (size_t)p * 512 * H + (size_t)colr * H + kof;
  bf16x8 Bf[4][4];                           // [gate u,i,o,g][kk]
  #pragma unroll
  for (int g4 = 0; g4 < 4; ++g4)
    #pragma unroll
    for (int kk = 0; kk < 4; ++kk)
      Bf[g4][kk] = *(const bf16x8*)(wb0 + (size_t)g4 * 128 * H + kk * 32);

  if (t < ROWSB) rowg[t] = (t < cnth) ? order[gs + t] : -1;
  __syncthreads();

  // ---- stage A: 128 rows x 128 bf16 (child_h + depth-masked extras) ----
  #pragma unroll
  for (int i = 0; i < (ROWSB * 16) / BLOCK; ++i) {
    int id = i * BLOCK + t;                  // 0..2047
    int row = id >> 4, c8 = id & 15;
    int g = rowg[row];
    float4 a0 = {0.f, 0.f, 0.f, 0.f}, a1 = {0.f, 0.f, 0.f, 0.f};
    if (g >= 0) {
      const float4* ph = (const float4*)(child_h + (size_t)g * H + c8 * 8);
      a0 = ph[0]; a1 = ph[1];
      int dep = depthp[g];
      if (dep == 1 || dep == 2) {
        const float* ep = (dep == 1) ? e1 : e2;
        const float4* pe = (const float4*)(ep + (size_t)g * H + c8 * 8);
        float4 b0 = pe[0], b1 = pe[1];
        a0.x += b0.x; a0.y += b0.y; a0.z += b0.z; a0.w += b0.w;
        a1.x += b1.x; a1.y += b1.y; a1.z += b1.z; a1.w += b1.w;
      }
    }
    bf16x8 v;
    v[0] = (short)f2bf(a0.x); v[1] = (short)f2bf(a0.y);
    v[2] = (short)f2bf(a0.z); v[3] = (short)f2bf(a0.w);
    v[4] = (short)f2bf(a1.x); v[5] = (short)f2bf(a1.y);
    v[6] = (short)f2bf(a1.z); v[7] = (short)f2bf(a1.w);
    int wb = (row * 256 + c8 * 16) ^ ((row & 7) << 4);
    *(bf16x8*)((char*)hs + wb) = v;
  }
  __syncthreads();

  const size_t NH = (size_t)N * H;
  const float bfv = b_f[p * H + colr];
  const float b_i = b_iou[colr], b_o = b_iou[H + colr], b_g = b_iou[2 * H + colr];

  const int nchunk = (cnth + 15) >> 4;
  for (int c = 0; c < nchunk; ++c) {
    const int r0 = c * 16;

    // A fragments: row = r0 + (l&15), k = kk*32 + (l>>4)*8 + j
    const int arow = r0 + l15;
    bf16x8 afr[4];
    #pragma unroll
    for (int kk = 0; kk < 4; ++kk) {
      int rb = (arow * 256 + kk * 64 + lhi * 16) ^ ((arow & 7) << 4);
      afr[kk] = *(const bf16x8*)((const char*)hs + rb);
    }

    // hoisted epilogue gathers — issue BEFORE MFMA so they overlap matrix work
    int gg[4]; float cc[4], hpv[4]; int mig[4];
    #pragma unroll
    for (int q = 0; q < 4; ++q) {
      int rr = r0 + lhi * 4 + q;
      gg[q] = (rr < cnth) ? rowg[rr] : -1;
    }
    #pragma unroll
    for (int q = 0; q < 4; ++q) {
      if (gg[q] >= 0) {
        size_t gi = (size_t)gg[q] * H + colr;
        cc[q] = child_c[gi];
        mig[q] = maskp[gg[q]];
        hpv[q] = h_prev[gi];
      } else { cc[q] = 0.f; mig[q] = 0; hpv[q] = 0.f; }
    }

    f32x4 au = {0.f, 0.f, 0.f, 0.f};
    f32x4 ai = {0.f, 0.f, 0.f, 0.f};
    f32x4 ao = {0.f, 0.f, 0.f, 0.f};
    f32x4 ag = {0.f, 0.f, 0.f, 0.f};
    #pragma unroll
    for (int kk = 0; kk < 4; ++kk) {
      au = __builtin_amdgcn_mfma_f32_16x16x32_bf16(afr[kk], Bf[0][kk], au, 0, 0, 0);
      ai = __builtin_amdgcn_mfma_f32_16x16x32_bf16(afr[kk], Bf[1][kk], ai, 0, 0, 0);
      ao = __builtin_amdgcn_mfma_f32_16x16x32_bf16(afr[kk], Bf[2][kk], ao, 0, 0, 0);
      ag = __builtin_amdgcn_mfma_f32_16x16x32_bf16(afr[kk], Bf[3][kk], ag, 0, 0, 0);
    }

    // epilogue: D row = (l>>4)*4 + q, col = l&15 (verified mapping)
    #pragma unroll
    for (int q = 0; q < 4; ++q) {
      if (gg[q] >= 0) {
        size_t gi = (size_t)gg[q] * H + colr;
        float u = au[q] + bfv;
        float iv = ai[q] + b_i;
        float ov = ao[q] + b_o;
        float gv = ag[q] + b_g;
        float f = sigm(u);
        float credv = f * cc[q];
        float cnew = sigm(iv) * tanh_f(gv) + credv;
        float hnew = sigm(ov) * tanh_f(cnew);
        float m = (float)mig[q];
        float hv = hpv[q] * m + (1.0f - m) * hnew;
        float cv = credv * m + (1.0f - m) * cnew;
        out[gi] = hv;
        out[NH + gi] = cv;
      }
    }
  }
}

extern "C" void kernel_launch(void* const* d_in, const int* in_sizes, int n_in,
                              void* d_out, int out_size, void* d_ws, size_t ws_size,
                              hipStream_t stream) {
  const float* child_h = (const float*)d_in[0];
  const float* child_c = (const float*)d_in[1];
  const float* e1      = (const float*)d_in[2];
  const float* e2      = (const float*)d_in[3];
  const float* h_prev  = (const float*)d_in[4];
  const int*   posp    = (const int*)d_in[5];
  const int*   depthp  = (const int*)d_in[6];
  const int*   maskp   = (const int*)d_in[7];
  const float* W_f     = (const float*)d_in[8];
  const float* b_f     = (const float*)d_in[9];
  const float* W_iou   = (const float*)d_in[10];
  const float* b_iou   = (const float*)d_in[11];
  float* out = (float*)d_out;
  int N = in_sizes[0] / H;
  int maxb = NPOS + N / ROWSB;

  // ws layout
  unsigned short* wt = (unsigned short*)d_ws;          // 655360 * 2B
  int* hist   = (int*)((char*)d_ws + (size_t)NPOS * 512 * H * 2);
  int* cursor = hist + 16;
  int* blkpos = hist + 32;
  int* blkgs  = blkpos + maxb;
  int* blkcnt = blkgs + maxb;
  int* order  = blkcnt + maxb;

  hipMemsetAsync(hist, 0, 64, stream);
  hipLaunchKernelGGL(prep_wt, dim3(NPOS * 16 + (NPOS * 384 * H) / 256), dim3(256), 0, stream,
                     W_f, W_iou, wt);
  hipLaunchKernelGGL(hist_k, dim3((N + 255) / 256), dim3(256), 0, stream, posp, hist, N);
  hipLaunchKernelGGL(scan_build, dim3(1), dim3(64), 0, stream,
                     hist, cursor, blkpos, blkgs, blkcnt, maxb);
  hipLaunchKernelGGL(scatter_idx, dim3((N + 255) / 256), dim3(256), 0, stream,
                     posp, cursor, order, N);
  hipLaunchKernelGGL(tree_lstm_main, dim3(maxb), dim3(BLOCK), 0, stream,
                     child_h, child_c, e1, e2, h_prev, depthp, maskp,
                     b_f, b_iou, wt, order, blkpos, blkgs, blkcnt, out, N);
}

// Round 6
// 55.548 us; speedup vs baseline: 5.0242x; 1.0098x over previous
//
#include <hip/hip_runtime.h>

#define H 128
#define NPOS 10
#define ROWSB 64
#define BLOCK 512

using bf16x8 = __attribute__((ext_vector_type(8))) short;
using f32x4  = __attribute__((ext_vector_type(4))) float;

__device__ __forceinline__ unsigned short f2bf(float f) {
  unsigned u = __float_as_uint(f);
  u += 0x7FFFu + ((u >> 16) & 1u);   // round-to-nearest-even
  return (unsigned short)(u >> 16);
}

__device__ __forceinline__ float sigm(float x) {
  return __builtin_amdgcn_rcpf(1.0f + __builtin_amdgcn_exp2f(-1.44269504f * x));
}
__device__ __forceinline__ float tanh_f(float x) {
  return 2.0f * __builtin_amdgcn_rcpf(1.0f + __builtin_amdgcn_exp2f(-2.88539008f * x)) - 1.0f;
}

// wt[p][j][k] bf16: j<128 -> u col j = W_f[p*H+k][j]; j>=128 -> iou row (j-128), col p*H+k
__global__ void prep_wt(const float* __restrict__ Wf, const float* __restrict__ Wiou,
                        unsigned short* __restrict__ wt) {
  int b = blockIdx.x, t = threadIdx.x;
  if (b < NPOS * 16) {
    __shared__ float tile[32][33];
    int p = b >> 4, jt = (b >> 2) & 3, kt = b & 3;
    int tx = t & 31, ty = t >> 5;            // 32 x 8
    #pragma unroll
    for (int it = 0; it < 4; ++it) {
      int krow = kt * 32 + ty + it * 8;
      int j = jt * 32 + tx;
      tile[ty + it * 8][tx] = Wf[(size_t)(p * H + krow) * H + j];
    }
    __syncthreads();
    #pragma unroll
    for (int it = 0; it < 4; ++it) {
      int j2 = jt * 32 + ty + it * 8;
      int k2 = kt * 32 + tx;
      wt[(size_t)p * 512 * H + (size_t)j2 * H + k2] = f2bf(tile[tx][ty + it * 8]);
    }
  } else {
    int id = (b - NPOS * 16) * 256 + t;
    int p = id / 49152;
    int r = id - p * 49152;
    int k = r & 127;
    float v = Wiou[(size_t)(r >> 7) * (NPOS * H) + p * H + k];
    wt[(size_t)p * 65536 + 16384 + r] = f2bf(v);
  }
}

__global__ void hist_k(const int* __restrict__ posp, int* __restrict__ hist, int N) {
  __shared__ int c[NPOS];
  int t = threadIdx.x;
  if (t < NPOS) c[t] = 0;
  __syncthreads();
  int i = blockIdx.x * 256 + t;
  if (i < N) atomicAdd(&c[posp[i]], 1);
  __syncthreads();
  if (t < NPOS && c[t] > 0) atomicAdd(&hist[t], c[t]);
}

__global__ void scan_build(const int* __restrict__ hist, int* __restrict__ cursor,
                           int* __restrict__ blkpos, int* __restrict__ blkgs,
                           int* __restrict__ blkcnt, int maxb) {
  __shared__ int base[NPOS + 1], bb[NPOS + 1];
  int t = threadIdx.x;
  if (t == 0) {
    int run = 0, rb = 0;
    for (int p = 0; p < NPOS; ++p) {
      base[p] = run; bb[p] = rb;
      run += hist[p];
      rb += (hist[p] + ROWSB - 1) / ROWSB;
    }
    base[NPOS] = run; bb[NPOS] = rb;
  }
  __syncthreads();
  if (t < NPOS) cursor[t] = base[t];
  int nb = bb[NPOS];
  for (int b = t; b < maxb; b += 64) {
    if (b < nb) {
      int p = 0;
      while (bb[p + 1] <= b) ++p;
      int s = (b - bb[p]) * ROWSB;
      blkpos[b] = p;
      blkgs[b] = base[p] + s;
      blkcnt[b] = min(ROWSB, hist[p] - s);
    } else {
      blkpos[b] = -1;
    }
  }
}

// LDS rank + per-(block,pos) range reservation.
// order entry packs: g (bits 0..15) | mask<<16 | (depth==1)<<17 | (depth==2)<<18
__global__ void scatter_idx(const int* __restrict__ posp, const int* __restrict__ depthp,
                            const int* __restrict__ maskp, int* __restrict__ cursor,
                            unsigned* __restrict__ order, int N) {
  __shared__ int c[NPOS], bb[NPOS];
  int t = threadIdx.x;
  if (t < NPOS) c[t] = 0;
  __syncthreads();
  int i = blockIdx.x * 256 + t;
  int p = -1, r = 0;
  unsigned e = 0;
  if (i < N) {
    p = posp[i];
    r = atomicAdd(&c[p], 1);
    int d = depthp[i];                       // coalesced
    int mk = maskp[i];                       // coalesced
    e = (unsigned)i | ((unsigned)mk << 16) |
        ((unsigned)(d == 1) << 17) | ((unsigned)(d == 2) << 18);
  }
  __syncthreads();
  if (t < NPOS) bb[t] = (c[t] > 0) ? atomicAdd(&cursor[t], c[t]) : 0;
  __syncthreads();
  if (p >= 0) order[bb[p] + r] = e;
}

__global__ __launch_bounds__(BLOCK, 4) void tree_lstm_main(
    const float* __restrict__ child_h, const float* __restrict__ child_c,
    const float* __restrict__ e1, const float* __restrict__ e2,
    const float* __restrict__ h_prev,
    const float* __restrict__ b_f, const float* __restrict__ b_iou,
    const unsigned short* __restrict__ wt,
    const unsigned* __restrict__ order, const int* __restrict__ blkpos,
    const int* __restrict__ blkgs, const int* __restrict__ blkcnt,
    float* __restrict__ out, int N) {

  const int b = blockIdx.x;
  const int p = blkpos[b];
  if (p < 0) return;
  const int gs = blkgs[b], cnth = blkcnt[b];

  __shared__ unsigned short hs[ROWSB * H];   // 16 KB, XOR-swizzled bf16 h_cat
  __shared__ unsigned rowg[ROWSB];

  const int t = threadIdx.x;
  const int wv = t >> 6, l = t & 63;
  const int l15 = l & 15, lhi = l >> 4;
  const int colr = wv * 16 + l15;            // wave's output column 0..127
  const int kof = lhi * 8;

  // ---- B panel into registers, pinned so LICM cannot sink the loads ----
  const unsigned short* wb0 = wt + (size_t)p * 512 * H + (size_t)colr * H + kof;
  bf16x8 Bf[4][4];                           // [gate u,i,o,g][kk] = 64 VGPRs
  #pragma unroll
  for (int g4 = 0; g4 < 4; ++g4)
    #pragma unroll
    for (int kk = 0; kk < 4; ++kk)
      Bf[g4][kk] = *(const bf16x8*)(wb0 + (size_t)g4 * 128 * H + kk * 32);

  if (t < ROWSB) rowg[t] = (t < cnth) ? order[gs + t] : 0xFFFFFFFFu;

  // pin B in VGPRs (asm may modify -> loads must complete here, no re-load later)
  #pragma unroll
  for (int g4 = 0; g4 < 4; ++g4)
    #pragma unroll
    for (int kk = 0; kk < 4; ++kk)
      asm volatile("" : "+v"(Bf[g4][kk]));

  __syncthreads();

  // ---- stage A: 64 rows x 128 bf16 (child_h + depth-class extras) ----
  #pragma unroll
  for (int i = 0; i < (ROWSB * 16) / BLOCK; ++i) {
    int id = i * BLOCK + t;
    int row = id >> 4, c8 = id & 15;
    unsigned e = rowg[row];
    float4 a0 = {0.f, 0.f, 0.f, 0.f}, a1 = {0.f, 0.f, 0.f, 0.f};
    if ((int)e >= 0) {
      int g = e & 0xFFFF;
      const float4* ph = (const float4*)(child_h + (size_t)g * H + c8 * 8);
      a0 = ph[0]; a1 = ph[1];
      if (e & (3u << 17)) {
        const float* ep = (e & (1u << 17)) ? e1 : e2;
        const float4* pe = (const float4*)(ep + (size_t)g * H + c8 * 8);
        float4 b0 = pe[0], b1 = pe[1];
        a0.x += b0.x; a0.y += b0.y; a0.z += b0.z; a0.w += b0.w;
        a1.x += b1.x; a1.y += b1.y; a1.z += b1.z; a1.w += b1.w;
      }
    }
    bf16x8 v;
    v[0] = (short)f2bf(a0.x); v[1] = (short)f2bf(a0.y);
    v[2] = (short)f2bf(a0.z); v[3] = (short)f2bf(a0.w);
    v[4] = (short)f2bf(a1.x); v[5] = (short)f2bf(a1.y);
    v[6] = (short)f2bf(a1.z); v[7] = (short)f2bf(a1.w);
    int wb = (row * 256 + c8 * 16) ^ ((row & 7) << 4);
    *(bf16x8*)((char*)hs + wb) = v;
  }
  __syncthreads();

  const size_t NH = (size_t)N * H;
  const float bfv = b_f[p * H + colr];
  const float b_i = b_iou[colr], b_o = b_iou[H + colr], b_g = b_iou[2 * H + colr];

  const int nchunk = (cnth + 15) >> 4;
  for (int c = 0; c < nchunk; ++c) {
    const int r0 = c * 16;

    // A fragments: row = r0 + (l&15), k = kk*32 + (l>>4)*8 + j
    const int arow = r0 + l15;
    bf16x8 afr[4];
    #pragma unroll
    for (int kk = 0; kk < 4; ++kk) {
      int rb = (arow * 256 + kk * 64 + lhi * 16) ^ ((arow & 7) << 4);
      afr[kk] = *(const bf16x8*)((const char*)hs + rb);
    }

    // hoisted epilogue gathers — issue BEFORE MFMA so they overlap matrix work
    unsigned gg[4]; float cc[4], hpv[4];
    #pragma unroll
    for (int q = 0; q < 4; ++q) {
      int rr = r0 + lhi * 4 + q;
      gg[q] = (rr < cnth) ? rowg[rr] : 0xFFFFFFFFu;
    }
    #pragma unroll
    for (int q = 0; q < 4; ++q) {
      if ((int)gg[q] >= 0) {
        size_t gi = (size_t)(gg[q] & 0xFFFF) * H + colr;
        cc[q] = child_c[gi];
        hpv[q] = h_prev[gi];
      } else { cc[q] = 0.f; hpv[q] = 0.f; }
    }

    f32x4 au = {0.f, 0.f, 0.f, 0.f};
    f32x4 ai = {0.f, 0.f, 0.f, 0.f};
    f32x4 ao = {0.f, 0.f, 0.f, 0.f};
    f32x4 ag = {0.f, 0.f, 0.f, 0.f};
    #pragma unroll
    for (int kk = 0; kk < 4; ++kk) {
      au = __builtin_amdgcn_mfma_f32_16x16x32_bf16(afr[kk], Bf[0][kk], au, 0, 0, 0);
      ai = __builtin_amdgcn_mfma_f32_16x16x32_bf16(afr[kk], Bf[1][kk], ai, 0, 0, 0);
      ao = __builtin_amdgcn_mfma_f32_16x16x32_bf16(afr[kk], Bf[2][kk], ao, 0, 0, 0);
      ag = __builtin_amdgcn_mfma_f32_16x16x32_bf16(afr[kk], Bf[3][kk], ag, 0, 0, 0);
    }

    // epilogue: D row = (l>>4)*4 + q, col = l&15 (verified mapping)
    #pragma unroll
    for (int q = 0; q < 4; ++q) {
      if ((int)gg[q] >= 0) {
        size_t gi = (size_t)(gg[q] & 0xFFFF) * H + colr;
        float u = au[q] + bfv;
        float iv = ai[q] + b_i;
        float ov = ao[q] + b_o;
        float gv = ag[q] + b_g;
        float f = sigm(u);
        float credv = f * cc[q];
        float cnew = sigm(iv) * tanh_f(gv) + credv;
        float hnew = sigm(ov) * tanh_f(cnew);
        float m = (float)((gg[q] >> 16) & 1u);
        float hv = hpv[q] * m + (1.0f - m) * hnew;
        float cv = credv * m + (1.0f - m) * cnew;
        out[gi] = hv;
        out[NH + gi] = cv;
      }
    }
  }
}

extern "C" void kernel_launch(void* const* d_in, const int* in_sizes, int n_in,
                              void* d_out, int out_size, void* d_ws, size_t ws_size,
                              hipStream_t stream) {
  const float* child_h = (const float*)d_in[0];
  const float* child_c = (const float*)d_in[1];
  const float* e1      = (const float*)d_in[2];
  const float* e2      = (const float*)d_in[3];
  const float* h_prev  = (const float*)d_in[4];
  const int*   posp    = (const int*)d_in[5];
  const int*   depthp  = (const int*)d_in[6];
  const int*   maskp   = (const int*)d_in[7];
  const float* W_f     = (const float*)d_in[8];
  const float* b_f     = (const float*)d_in[9];
  const float* W_iou   = (const float*)d_in[10];
  const float* b_iou   = (const float*)d_in[11];
  float* out = (float*)d_out;
  int N = in_sizes[0] / H;
  int maxb = NPOS + N / ROWSB;

  // ws layout
  unsigned short* wt = (unsigned short*)d_ws;          // 655360 * 2B
  int* hist   = (int*)((char*)d_ws + (size_t)NPOS * 512 * H * 2);
  int* cursor = hist + 16;
  int* blkpos = hist + 32;
  int* blkgs  = blkpos + maxb;
  int* blkcnt = blkgs + maxb;
  unsigned* order = (unsigned*)(blkcnt + maxb);

  hipMemsetAsync(hist, 0, 64, stream);
  hipLaunchKernelGGL(prep_wt, dim3(NPOS * 16 + (NPOS * 384 * H) / 256), dim3(256), 0, stream,
                     W_f, W_iou, wt);
  hipLaunchKernelGGL(hist_k, dim3((N + 255) / 256), dim3(256), 0, stream, posp, hist, N);
  hipLaunchKernelGGL(scan_build, dim3(1), dim3(64), 0, stream,
                     hist, cursor, blkpos, blkgs, blkcnt, maxb);
  hipLaunchKernelGGL(scatter_idx, dim3((N + 255) / 256), dim3(256), 0, stream,
                     posp, depthp, maskp, cursor, order, N);
  hipLaunchKernelGGL(tree_lstm_main, dim3(maxb), dim3(BLOCK), 0, stream,
                     child_h, child_c, e1, e2, h_prev,
                     b_f, b_iou, wt, order, blkpos, blkgs, blkcnt, out, N);
}